// Round 8
// baseline (35206.845 us; speedup 1.0000x reference)
//
#include <hip/hip_runtime.h>
#include <hip/hip_fp16.h>
#include <math.h>

// LSTM_11089605558768: T=16384 sequential steps, H=512, IN=32, OUT=1.
// Persistent scan, 32 wgs x 256 threads. Exchange = proven LLC packet
// protocol (R2/R6): 4B self-validating packets tag16<<16 | fp16(h), parity
// double-buffered, sc0+sc1 (XCD-L2 shortcuts falsified R4/R5).
//
// R8 = R7 gate-parallel STRUCTURE + R6 proven NUMERICS.
//  R7's absmax 0.204 failure isolated to fp16 weights (systematic recurrence-
//  map perturbation integrated over 16384 steps). fp16 stays ONLY on the wire.
//  - wave w = gate class (0=i,1=f,2=g tanh,3=o); lane (q=l>>4, j=l&15) covers
//    k-quarter q of row j. fp32 weights, 136 VGPR-pinned per lane.
//  - Row sum: 2-step shfl_xor butterfly (no LDS reduction round-trip).
//  - Activations wave-parallel (1 transcendental on the serial chain, not 4).
//  - c/h update replicated in lanes 0-15 of all 4 waves; publish split:
//    wave w stores packets [4w,4w+4) - one coalesced 16B line per wg.
//  - LDS h fp32; quarter base stride 136 floats -> banks {0,8,16,24}+i*4,
//    conflict-free float4 reads (16-lane broadcast groups).

#define T_STEPS 16384
#define IN_DIM  32
#define H_DIM   512
#define SLOTS   32
#define H_SLICE 16      // H_DIM / SLOTS
#define KTOT    544     // H_DIM + IN_DIM
#define QCHUNK  136     // per-lane k-chunk (KTOT/4)

typedef unsigned int uint4v __attribute__((ext_vector_type(4)));

__device__ __forceinline__ float fast_sigmoid(float v) {
  return 1.0f / (1.0f + __expf(-v));
}
__device__ __forceinline__ float fast_tanh(float v) {
  return 2.0f / (1.0f + __expf(-2.0f * v)) - 1.0f;  // 2*sigmoid(2x)-1
}

// --- packet I/O (LLC-coherent: sc0 sc1) ------------------------------------
__device__ __forceinline__ void store_pkt(unsigned int* p, unsigned int v) {
  asm volatile("global_store_dword %0, %1, off sc0 sc1"
               :: "v"(p), "v"(v) : "memory");
}
__device__ __forceinline__ uint4v load_pkt4(const unsigned int* p) {
  uint4v r;
  asm volatile("global_load_dwordx4 %0, %1, off sc0 sc1\n\ts_waitcnt vmcnt(0)"
               : "=&v"(r) : "v"(p) : "memory");
  return r;
}

__device__ __forceinline__ float h16(unsigned int lo16) {
  return __half2float(__ushort_as_half((unsigned short)(lo16 & 0xFFFFu)));
}

__launch_bounds__(256, 1)
__global__ void lstm_scan_kernel(
    const float* __restrict__ x,     // [T, 32]
    const float* __restrict__ Wih,   // [2048, 32]
    const float* __restrict__ Whh,   // [2048, 512]
    const float* __restrict__ bih,   // [2048]
    const float* __restrict__ bhh,   // [2048]
    const float* __restrict__ Wlin,  // [512]
    const float* __restrict__ blin,  // [1]
    float* __restrict__ out,         // [1]
    unsigned int* pub)               // [2][512] 4B packets (d_ws)
{
  const int slot = blockIdx.x;       // 0..31
  const int tid  = threadIdx.x;
  const int w    = tid >> 6;   // wave = gate: 0=i, 1=f, 2=g(tanh), 3=o
  const int l    = tid & 63;
  const int q    = l >> 4;     // k-quarter 0..3
  const int j    = l & 15;     // row within own slice

  __shared__ __align__(16) float hshm[KTOT];  // [0,512)=h(t) fp32, [512,544)=x_t
  __shared__ __align__(16) float actsh[64];   // [j][gate]
  __shared__ float red[256];                  // final projection scratch

  const int R = w * H_DIM + slot * H_SLICE + j;  // global gate row

  // ---- persistent fp32 weight slice -> VGPRs, pinned ----
  float wreg[QCHUNK];
  #pragma unroll
  for (int i = 0; i < QCHUNK; ++i) {
    const int k = q * QCHUNK + i;
    wreg[i] = (k < H_DIM) ? Whh[R * H_DIM + k]
                          : Wih[R * IN_DIM + (k - H_DIM)];
  }
  #pragma unroll
  for (int i = 0; i < QCHUNK; ++i)
    asm volatile("v_mov_b32 %0, %0" : "+v"(wreg[i]));  // no remat in loop

  const float bias = bih[R] + bhh[R];

  float c = 0.0f;  // cell state, replicated in lanes j of every wave

  // Pollers: tid<128 poll 4 packets each; own-slice group handled by epilogue.
  const bool poller = (tid < 128) && ((tid >> 2) != slot);
  if (tid < H_SLICE) hshm[slot * H_SLICE + tid] = 0.0f;  // h(0) own slice

  for (int t = 0; t < T_STEPS; ++t) {
    float xv = (tid < IN_DIM) ? x[t * IN_DIM + tid] : 0.0f;  // overlaps poll

    // ---- gather h(t): poll 4 self-validating packets, cvt fp16->fp32 ----
    if (poller) {
      const unsigned int* p = pub + (t & 1) * H_DIM + tid * 4;
      const unsigned int tg = (unsigned int)t;
      uint4v r;
      for (;;) {
        r = load_pkt4(p);
        if ((r.x >> 16) == tg && (r.y >> 16) == tg &&
            (r.z >> 16) == tg && (r.w >> 16) == tg) break;
      }
      float4 hv4;
      hv4.x = h16(r.x); hv4.y = h16(r.y); hv4.z = h16(r.z); hv4.w = h16(r.w);
      *(float4*)(hshm + tid * 4) = hv4;
    }
    if (tid < IN_DIM) hshm[H_DIM + tid] = xv;
    __syncthreads();  // barrier B: h(t)+x_t staged (fp32)

    // ---- matvec: lane (q,j) of wave w: row R, k in [136q, 136q+136) ----
    const float4* hv = (const float4*)(hshm + q * QCHUNK);  // 16B-aligned
    float a0 = 0.f, a1 = 0.f, a2 = 0.f, a3 = 0.f;
    #pragma unroll
    for (int i = 0; i < QCHUNK / 4; ++i) {
      const float4 h4 = hv[i];  // 16-lane broadcast; quarters bank-disjoint
      a0 = fmaf(wreg[4 * i + 0], h4.x, a0);
      a1 = fmaf(wreg[4 * i + 1], h4.y, a1);
      a2 = fmaf(wreg[4 * i + 2], h4.z, a2);
      a3 = fmaf(wreg[4 * i + 3], h4.w, a3);
    }
    float acc = (a0 + a1) + (a2 + a3);
    // butterfly across k-quarters (lanes j, 16+j, 32+j, 48+j)
    acc += __shfl_xor(acc, 16, 64);
    acc += __shfl_xor(acc, 32, 64);
    const float g = acc + bias;
    const float act = (w == 2) ? fast_tanh(g) : fast_sigmoid(g);
    if (l < 16) actsh[l * 4 + w] = act;  // 2-way bank alias = free
    __syncthreads();  // barrier C: 64 activated gate values ready

    // ---- replicated c/h update (lanes 0-15, all waves); split publish ----
    if (l < 16) {
      const float4 a4 = *(const float4*)(actsh + l * 4);  // i,f,g,o
      c = a4.y * c + a4.x * a4.z;
      const float h = a4.w * fast_tanh(c);
      if (w == 0) hshm[slot * H_SLICE + l] = h;  // own-slice fp32 (R6-proven)
      if ((l >> 2) == w) {  // wave w publishes packets [4w, 4w+4)
        const unsigned int pkt =
            ((unsigned int)(t + 1) << 16) |
            (unsigned int)__half_as_ushort(__float2half_rn(h));
        store_pkt(pub + ((t + 1) & 1) * H_DIM + slot * H_SLICE + l, pkt);
      }
    }
    // actsh(t) reads precede barrier B(t+1); actsh(t+1) writes follow it.
  }

  // ---- slot 0: final projection out = h(T) . Wlin + blin ----
  if (slot == 0) {
    if (poller) {
      const unsigned int* p = pub + (T_STEPS & 1) * H_DIM + tid * 4;
      const unsigned int tg = (unsigned int)T_STEPS;
      uint4v r;
      for (;;) {
        r = load_pkt4(p);
        if ((r.x >> 16) == tg && (r.y >> 16) == tg &&
            (r.z >> 16) == tg && (r.w >> 16) == tg) break;
      }
      float4 hv4;
      hv4.x = h16(r.x); hv4.y = h16(r.y); hv4.z = h16(r.z); hv4.w = h16(r.w);
      *(float4*)(hshm + tid * 4) = hv4;
    }
    __syncthreads();
    red[tid] = hshm[2 * tid] * Wlin[2 * tid] +
               hshm[2 * tid + 1] * Wlin[2 * tid + 1];
    __syncthreads();
    if (w == 0) {
      float s = red[l] + red[64 + l] + red[128 + l] + red[192 + l];
      #pragma unroll
      for (int off = 32; off > 0; off >>= 1) s += __shfl_down(s, off, 64);
      if (l == 0) out[0] = s + blin[0];
    }
  }
}

extern "C" void kernel_launch(void* const* d_in, const int* in_sizes, int n_in,
                              void* d_out, int out_size, void* d_ws, size_t ws_size,
                              hipStream_t stream) {
  const float* x    = (const float*)d_in[0];
  const float* Wih  = (const float*)d_in[1];
  const float* Whh  = (const float*)d_in[2];
  const float* bih  = (const float*)d_in[3];
  const float* bhh  = (const float*)d_in[4];
  const float* Wlin = (const float*)d_in[5];
  const float* blin = (const float*)d_in[6];
  float* out = (float*)d_out;

  unsigned int* pub = (unsigned int*)d_ws;  // [2][512] u32 = 4096 B

  // d_ws re-poisoned 0xAA before every timed call; zeroed pub encodes
  // (tag=0, h=0) == the initial hidden state.
  hipMemsetAsync(d_ws, 0, 4096, stream);
  hipLaunchKernelGGL(lstm_scan_kernel, dim3(SLOTS), dim3(256), 0, stream,
                     x, Wih, Whh, bih, bhh, Wlin, blin, out, pub);
}

// Round 9
// 28720.523 us; speedup vs baseline: 1.2258x; 1.2258x over previous
//
#include <hip/hip_runtime.h>
#include <hip/hip_fp16.h>
#include <math.h>

// LSTM_11089605558768: T=16384 sequential steps, H=512, IN=32, OUT=1.
// Persistent scan, 32 wgs x 256 threads; wave w = k-chunk (R6-proven mapping,
// VGPR=144 with weights resident), lane = gate row. Exchange = proven LLC
// packet protocol: 4B self-validating packets tag16<<16 | fp16(h), parity
// double-buffered, sc0+sc1 (XCD-L2 shortcuts falsified R4/R5).
//
// R9 = R6 EXACTLY, except h(t)/x_t staged in LDS as fp16:
//  - pollers deposit raw packet fp16 bits (no cvt on the poll path),
//  - per-wave LDS reads: 17 ds_read_b128 instead of 34 (DS pipe ~1630->~820
//    cyc/step; DS was the largest compute-leg term),
//  - unpack with v_cvt_f32_f16 in the FMA loop (VALU, overlaps DS),
//  - weights stay fp32 (R7 proved fp16 weights = systematic map perturbation
//    -> 0.2 absmax divergence; wire/staging fp16 is proven benign in R6).
// R8 lesson: keep R6's wave-uniform weight-chunk loader verbatim — the
// per-lane-varying variant made the allocator spill wreg (VGPR 88, scratch
// traffic doubled WRITE_SIZE).

#define T_STEPS 16384
#define IN_DIM  32
#define H_DIM   512
#define SLOTS   32
#define H_SLICE 16      // H_DIM / SLOTS
#define KTOT    544     // H_DIM + IN_DIM
#define CHUNK   136     // KTOT / 4 waves
#define NV128   17      // CHUNK halves per wave / 8

typedef unsigned int uint4v __attribute__((ext_vector_type(4)));
typedef unsigned int uint2v __attribute__((ext_vector_type(2)));

__device__ __forceinline__ float fast_sigmoid(float v) {
  return 1.0f / (1.0f + __expf(-v));
}
__device__ __forceinline__ float fast_tanh(float v) {
  return 2.0f / (1.0f + __expf(-2.0f * v)) - 1.0f;  // 2*sigmoid(2x)-1
}

// --- packet I/O (LLC-coherent: sc0 sc1) ------------------------------------
__device__ __forceinline__ void store_pkt(unsigned int* p, unsigned int v) {
  asm volatile("global_store_dword %0, %1, off sc0 sc1"
               :: "v"(p), "v"(v) : "memory");
}
__device__ __forceinline__ uint4v load_pkt4(const unsigned int* p) {
  uint4v r;
  asm volatile("global_load_dwordx4 %0, %1, off sc0 sc1\n\ts_waitcnt vmcnt(0)"
               : "=&v"(r) : "v"(p) : "memory");
  return r;
}

__device__ __forceinline__ float2 up2(unsigned int u) {  // 2 fp16 -> 2 fp32
  return __half22float2(__builtin_bit_cast(__half2, u));
}

__launch_bounds__(256, 1)
__global__ void lstm_scan_kernel(
    const float* __restrict__ x,     // [T, 32]
    const float* __restrict__ Wih,   // [2048, 32]
    const float* __restrict__ Whh,   // [2048, 512]
    const float* __restrict__ bih,   // [2048]
    const float* __restrict__ bhh,   // [2048]
    const float* __restrict__ Wlin,  // [512]
    const float* __restrict__ blin,  // [1]
    float* __restrict__ out,         // [1]
    unsigned int* pub)               // [2][512] 4B packets (d_ws)
{
  const int slot = blockIdx.x;       // 0..31
  const int tid  = threadIdx.x;
  const int w    = tid >> 6;   // wave 0..3 -> k-chunk
  const int l    = tid & 63;   // lane -> local gate row

  __shared__ __align__(16) _Float16 hshm[KTOT];  // [0,512)=h(t), [512,544)=x_t (fp16)
  __shared__ float red[256];                     // per-wave partials

  // local row l: 0..15 = i, 16..31 = f, 32..47 = g, 48..63 = o
  const int R = (l >> 4) * H_DIM + slot * H_SLICE + (l & 15);

  // ---- persistent fp32 weight slice -> VGPRs (R6-verbatim loader + pin) ----
  float wreg[CHUNK];
  #pragma unroll
  for (int j = 0; j < CHUNK; ++j) {
    const int k = w * CHUNK + j;
    wreg[j] = (k < H_DIM) ? Whh[R * H_DIM + k]
                          : Wih[R * IN_DIM + (k - H_DIM)];
  }
  #pragma unroll
  for (int j = 0; j < CHUNK; ++j)
    asm volatile("v_mov_b32 %0, %0" : "+v"(wreg[j]));  // no remat in loop

  const float bias = (w == 0) ? (bih[R] + bhh[R]) : 0.0f;

  float c = 0.0f;  // cell state: wave 0, lanes 0..15 (h index slot*16 + l)

  // Pollers: tid<128 poll 4 packets each; own-slice group fed by epilogue.
  const bool poller = (tid < 128) && ((tid >> 2) != slot);
  if (tid < H_SLICE) hshm[slot * H_SLICE + tid] = (_Float16)0.0f;  // h(0)

  for (int t = 0; t < T_STEPS; ++t) {
    float xv = (tid < IN_DIM) ? x[t * IN_DIM + tid] : 0.0f;  // overlaps poll

    // ---- gather h(t): poll 4 packets, deposit RAW fp16 bits ----
    if (poller) {
      const unsigned int* p = pub + (t & 1) * H_DIM + tid * 4;
      const unsigned int tg = (unsigned int)t;
      uint4v r;
      for (;;) {
        r = load_pkt4(p);
        if ((r.x >> 16) == tg && (r.y >> 16) == tg &&
            (r.z >> 16) == tg && (r.w >> 16) == tg) break;
      }
      uint2v pk;
      pk.x = (r.x & 0xFFFFu) | (r.y << 16);
      pk.y = (r.z & 0xFFFFu) | (r.w << 16);
      ((uint2v*)hshm)[tid] = pk;   // halves [4tid, 4tid+4)
    }
    if (tid < IN_DIM) hshm[H_DIM + tid] = (_Float16)xv;
    __syncthreads();  // barrier B: h(t)+x_t staged (fp16)

    // ---- matvec: wave w covers k in [136w, 136w+136), row l ----
    const uint4v* hv = (const uint4v*)hshm + w * NV128;  // 272B offset, 16B-aligned
    float a0 = 0.f, a1 = 0.f, a2 = 0.f, a3 = 0.f;
    #pragma unroll
    for (int i = 0; i < NV128; ++i) {
      const uint4v hb = hv[i];  // 8 halves, wave-uniform broadcast read
      const float2 f0 = up2(hb.x);
      const float2 f1 = up2(hb.y);
      const float2 f2 = up2(hb.z);
      const float2 f3 = up2(hb.w);
      a0 = fmaf(wreg[8 * i + 0], f0.x, a0);
      a1 = fmaf(wreg[8 * i + 1], f0.y, a1);
      a2 = fmaf(wreg[8 * i + 2], f1.x, a2);
      a3 = fmaf(wreg[8 * i + 3], f1.y, a3);
      a0 = fmaf(wreg[8 * i + 4], f2.x, a0);
      a1 = fmaf(wreg[8 * i + 5], f2.y, a1);
      a2 = fmaf(wreg[8 * i + 6], f3.x, a2);
      a3 = fmaf(wreg[8 * i + 7], f3.y, a3);
    }
    red[w * 64 + l] = (a0 + a1) + (a2 + a3);
    __syncthreads();  // barrier C: partials ready

    // ---- wave 0: activate (all 64 lanes), update c/h, publish ----
    if (w == 0) {
      const float g = bias + red[l] + red[64 + l] + red[128 + l] + red[192 + l];
      // lanes 0-15: i (sig), 16-31: f (sig), 32-47: g (tanh), 48-63: o (sig)
      const float act = (l < 32 || l >= 48) ? fast_sigmoid(g) : fast_tanh(g);
      const int j = l & 15;
      const float ig = __shfl(act, j, 64);
      const float fg = __shfl(act, j + 16, 64);
      const float gt = __shfl(act, j + 32, 64);
      const float og = __shfl(act, j + 48, 64);
      if (l < H_SLICE) {
        c = fg * c + ig * gt;
        const float h = og * fast_tanh(c);
        const __half hh = __float2half_rn(h);
        hshm[slot * H_SLICE + l] =
            __builtin_bit_cast(_Float16, hh);      // own slice, fp16 (wire prec)
        const unsigned int pkt =
            ((unsigned int)(t + 1) << 16) |
            (unsigned int)__half_as_ushort(hh);
        store_pkt(pub + ((t + 1) & 1) * H_DIM + slot * H_SLICE + l, pkt);
      }
    }
    // hshm/red hazards covered by barriers B/C (disjoint index sets).
  }

  // ---- slot 0: final projection out = h(T) . Wlin + blin ----
  if (slot == 0) {
    if (poller) {
      const unsigned int* p = pub + (T_STEPS & 1) * H_DIM + tid * 4;
      const unsigned int tg = (unsigned int)T_STEPS;
      uint4v r;
      for (;;) {
        r = load_pkt4(p);
        if ((r.x >> 16) == tg && (r.y >> 16) == tg &&
            (r.z >> 16) == tg && (r.w >> 16) == tg) break;
      }
      uint2v pk;
      pk.x = (r.x & 0xFFFFu) | (r.y << 16);
      pk.y = (r.z & 0xFFFFu) | (r.w << 16);
      ((uint2v*)hshm)[tid] = pk;
    }
    __syncthreads();
    red[tid] = (float)hshm[2 * tid] * Wlin[2 * tid] +
               (float)hshm[2 * tid + 1] * Wlin[2 * tid + 1];
    __syncthreads();
    if (w == 0) {
      float s = red[l] + red[64 + l] + red[128 + l] + red[192 + l];
      #pragma unroll
      for (int off = 32; off > 0; off >>= 1) s += __shfl_down(s, off, 64);
      if (l == 0) out[0] = s + blin[0];
    }
  }
}

extern "C" void kernel_launch(void* const* d_in, const int* in_sizes, int n_in,
                              void* d_out, int out_size, void* d_ws, size_t ws_size,
                              hipStream_t stream) {
  const float* x    = (const float*)d_in[0];
  const float* Wih  = (const float*)d_in[1];
  const float* Whh  = (const float*)d_in[2];
  const float* bih  = (const float*)d_in[3];
  const float* bhh  = (const float*)d_in[4];
  const float* Wlin = (const float*)d_in[5];
  const float* blin = (const float*)d_in[6];
  float* out = (float*)d_out;

  unsigned int* pub = (unsigned int*)d_ws;  // [2][512] u32 = 4096 B

  // d_ws re-poisoned 0xAA before every timed call; zeroed pub encodes
  // (tag=0, h=0) == the initial hidden state.
  hipMemsetAsync(d_ws, 0, 4096, stream);
  hipLaunchKernelGGL(lstm_scan_kernel, dim3(SLOTS), dim3(256), 0, stream,
                     x, Wih, Whh, bih, bhh, Wlin, blin, out, pub);
}